// Round 4
// baseline (84.302 us; speedup 1.0000x reference)
//
#include <hip/hip_runtime.h>
#include <stdint.h>

// Dual quantized EMA scan, chunked with redundant warmup.
// State in scaled domain Y = y*2^23: 24-bit quantize = one v_rndne.
// R4: global_load_lds 4-deep group ring + counted vmcnt. Register double-
// buffering capped in-flight at 16 KB/wave (R1-R3 show demand BW tracks
// in-flight bytes/CU); LDS ring holds 48 KB/wave of loads in flight with no
// VGPR cost. Waits count only younger LOADS (stores may complete out of
// order): if group g unlanded, its 48 younger in-order loads are all
// outstanding -> vmcnt > 48 -> wait cannot pass early.

typedef float fx4 __attribute__((ext_vector_type(4)));

constexpr int T = 8192;
constexpr int C = 256;
constexpr int S = 256;          // chunk length (output rows per block)
constexpr int W = 128;          // warmup length (alpha^128*|state| << thr)
constexpr int U = 8;            // rows per group
constexpr int G = 4;            // ring depth in groups (64 KB LDS)
constexpr int NCHUNK = T / S;   // 32
constexpr int RS = C / 4;       // row stride in fx4 units = 64

constexpr float ALPHA = 0.95f;

__device__ __forceinline__ void vwait48() { asm volatile("s_waitcnt vmcnt(48)" ::: "memory"); }
__device__ __forceinline__ void vwait32() { asm volatile("s_waitcnt vmcnt(32)" ::: "memory"); }
__device__ __forceinline__ void vwait16() { asm volatile("s_waitcnt vmcnt(16)" ::: "memory"); }
__device__ __forceinline__ void vwait0()  { asm volatile("s_waitcnt vmcnt(0)"  ::: "memory"); }
__device__ __forceinline__ void lwait0()  { asm volatile("s_waitcnt lgkmcnt(0)" ::: "memory"); }

__device__ __forceinline__ void gload16(const fx4* g, fx4* l) {
  // global src is per-lane; LDS dest is wave-uniform base + lane*16 (linear).
  __builtin_amdgcn_global_load_lds((const __attribute__((address_space(1))) uint32_t*)g,
                                   (__attribute__((address_space(3))) uint32_t*)l,
                                   16, 0, 0);
}

template <bool WARM>
__device__ __forceinline__ void run_chunk(const fx4* __restrict__ xg,
                                          const fx4* __restrict__ yg,
                                          fx4* __restrict__ og,
                                          fx4 (*ring)[2][U][64],
                                          int lane) {
  constexpr int WG = WARM ? W / U : 0;   // 16 or 0 warmup groups
  constexpr int NG = WG + S / U;         // 48 or 32 total groups
  const float Kc  = (1.0f - ALPHA) * 8388608.0f;  // (1-a) * 2^23
  const float C8  = 1.0f / 256.0f;                // 2^23 -> 2^15 domain
  const float I16 = 1.0f / 32768.0f;

  fx4 Y0 = {0.f, 0.f, 0.f, 0.f}, Y1 = {0.f, 0.f, 0.f, 0.f};

  auto issue = [&](int g) {
    const int sl = g & (G - 1);
    const fx4* xr = xg + (size_t)g * U * RS;
    const fx4* yr = yg + (size_t)g * U * RS;
#pragma unroll
    for (int r = 0; r < U; ++r) {
      gload16(xr + (size_t)r * RS, &ring[sl][0][r][0]);
      gload16(yr + (size_t)r * RS, &ring[sl][1][r][0]);
    }
  };

  issue(0); issue(1); issue(2); issue(3);

#pragma unroll 1
  for (int g = 0; g < NG; ++g) {
    const int rem = NG - 1 - g;
    if (rem >= 3)      vwait48();   // groups g+1..g+3 (48 loads) younger
    else if (rem == 2) vwait32();
    else if (rem == 1) vwait16();
    else               vwait0();

    const int sl = g & (G - 1);
#pragma unroll
    for (int r = 0; r < U; ++r) {
      fx4 xv = ring[sl][0][r][lane];
      fx4 yv = ring[sl][1][r][lane];
      fx4 o;
#pragma unroll
      for (int j = 0; j < 4; ++j) {
        Y0[j] = rintf(fmaf(ALPHA, Y0[j], Kc * xv[j]));  // 24b EMA (scaled)
        Y1[j] = rintf(fmaf(ALPHA, Y1[j], Kc * yv[j]));
        o[j]  = (rintf(Y0[j] * C8) + rintf(Y1[j] * C8)) * I16;
      }
      if (g >= WG)
        __builtin_nontemporal_store(o, og + (size_t)(g - WG) * U * RS + (size_t)r * RS);
    }

    if (g + G < NG) {
      lwait0();          // ds_reads of slot sl fully landed in VGPRs
      issue(g + G);      // safe to DMA-overwrite slot sl
    }
  }
}

__global__ __launch_bounds__(64) void I24DualEMA_kernel(const fx4* __restrict__ x,
                                                        const fx4* __restrict__ y,
                                                        fx4* __restrict__ out) {
  __shared__ fx4 ring[G][2][U][64];   // 64 KB
  const int lane  = threadIdx.x;            // 0..63 -> channel quad
  const int bid   = blockIdx.x;
  const int chunk = bid & (NCHUNK - 1);
  const int b     = bid >> 5;
  const int t0    = chunk * S;

  if (chunk == 0) {
    const size_t base = (size_t)b * T * RS + lane;
    run_chunk<false>(x + base, y + base, out + base, ring, lane);
  } else {
    const size_t baseIn  = ((size_t)b * T + (size_t)(t0 - W)) * RS + lane;
    const size_t baseOut = ((size_t)b * T + (size_t)t0) * RS + lane;
    run_chunk<true>(x + baseIn, y + baseIn, out + baseOut, ring, lane);
  }
}

extern "C" void kernel_launch(void* const* d_in, const int* in_sizes, int n_in,
                              void* d_out, int out_size, void* d_ws, size_t ws_size,
                              hipStream_t stream) {
  const fx4* x = (const fx4*)d_in[0];
  const fx4* y = (const fx4*)d_in[1];
  fx4* out = (fx4*)d_out;
  const int B = in_sizes[0] / (T * C);       // 16
  const int nblocks = B * NCHUNK;            // 512
  I24DualEMA_kernel<<<dim3(nblocks), dim3(64), 0, stream>>>(x, y, out);
}

// Round 5
// 70.832 us; speedup vs baseline: 1.1902x; 1.1902x over previous
//
#include <hip/hip_runtime.h>

// Dual quantized EMA scan, chunked with redundant warmup.
// State in scaled domain Y = y*2^23: 24-bit quantize = one v_rndne.
// R5: demand-reduction round. R2/R3/R4 all converge at ~6.4-6.7 TB/s demand
// BW (reads incl. L3 hits + writes) -> memory ceiling, so cut demand:
//   S 256->512, W 128->96  => read amp 1.5 -> 1.1875 (537 -> 453 MB demand).
// alpha^96 * max|boundary state| ~ 5e-4 added error, threshold 2.4e-3.
// Row split in half across blocks (fx2/lane) keeps 512 blocks = 2 waves/CU
// and 32 KB/CU in flight (the R3-proven operating point). LDS ring reverted
// (R4: proven neutral).

typedef float fx2 __attribute__((ext_vector_type(2)));

constexpr int T = 8192;
constexpr int C = 256;
constexpr int S = 512;          // chunk length (output rows per block)
constexpr int W = 96;           // warmup length
constexpr int U = 16;           // rows per load/compute group
constexpr int NCHUNK = T / S;   // 16
constexpr int RS2 = C / 2;      // row stride in fx2 units = 128

constexpr float ALPHA = 0.95f;

__device__ __forceinline__ void load_group(const fx2* __restrict__ xq,
                                           const fx2* __restrict__ yq,
                                           fx2* xv, fx2* yv) {
#pragma unroll
  for (int i = 0; i < U; ++i) {
    xv[i] = xq[(size_t)i * RS2];
    yv[i] = yq[(size_t)i * RS2];
  }
}

template <bool STORE>
__device__ __forceinline__ void proc_group(fx2& Y0, fx2& Y1,
                                           const fx2* xv, const fx2* yv,
                                           fx2* __restrict__ oq) {
  const float K   = (1.0f - ALPHA) * 8388608.0f;  // (1-a) * 2^23
  const float C8  = 1.0f / 256.0f;                // 2^23 -> 2^15 domain
  const float I16 = 1.0f / 32768.0f;
#pragma unroll
  for (int i = 0; i < U; ++i) {
    fx2 o;
#pragma unroll
    for (int j = 0; j < 2; ++j) {
      Y0[j] = rintf(fmaf(ALPHA, Y0[j], K * xv[i][j]));  // 24b EMA (scaled)
      Y1[j] = rintf(fmaf(ALPHA, Y1[j], K * yv[i][j]));
      o[j]  = (rintf(Y0[j] * C8) + rintf(Y1[j] * C8)) * I16;
    }
    if (STORE) __builtin_nontemporal_store(o, &oq[(size_t)i * RS2]);
  }
}

template <bool WARM>
__device__ __forceinline__ void run_chunk(const fx2* __restrict__ xp,
                                          const fx2* __restrict__ yp,
                                          fx2* __restrict__ op) {
  constexpr int WG = WARM ? (W / U) : 0;  // 6 or 0 warmup groups (even)
  constexpr int NG = WG + S / U;          // total groups: 38 or 32
  fx2 xa[U], ya[U], xb[U], yb[U];
  fx2 Y0 = {0.f, 0.f}, Y1 = {0.f, 0.f};

  load_group(xp, yp, xa, ya);

  if (WARM) {
#pragma unroll 1
    for (int g = 0; g < WG; g += 2) {
      load_group(xp + (size_t)(g + 1) * U * RS2, yp + (size_t)(g + 1) * U * RS2, xb, yb);
      proc_group<false>(Y0, Y1, xa, ya, nullptr);
      load_group(xp + (size_t)(g + 2) * U * RS2, yp + (size_t)(g + 2) * U * RS2, xa, ya);
      proc_group<false>(Y0, Y1, xb, yb, nullptr);
    }
  }

#pragma unroll 1
  for (int g = WG; g < NG; g += 2) {
    load_group(xp + (size_t)(g + 1) * U * RS2, yp + (size_t)(g + 1) * U * RS2, xb, yb);
    proc_group<true>(Y0, Y1, xa, ya, op + (size_t)(g - WG) * U * RS2);
    if (g + 2 < NG)
      load_group(xp + (size_t)(g + 2) * U * RS2, yp + (size_t)(g + 2) * U * RS2, xa, ya);
    proc_group<true>(Y0, Y1, xb, yb, op + (size_t)(g + 1 - WG) * U * RS2);
  }
}

__global__ __launch_bounds__(64) void I24DualEMA_kernel(const fx2* __restrict__ x,
                                                        const fx2* __restrict__ y,
                                                        fx2* __restrict__ out) {
  const int lane  = threadIdx.x;            // 0..63 -> fx2 within half-row
  const int bid   = blockIdx.x;
  const int chalf = bid & 1;                // which half of the C=256 row
  const int chunk = (bid >> 1) & (NCHUNK - 1);
  const int b     = bid >> 5;
  const int col   = (chalf << 6) | lane;    // fx2 column index in row
  const long t0   = (long)chunk * S;

  if (chunk == 0) {
    const size_t base = (size_t)b * T * RS2 + col;
    run_chunk<false>(x + base, y + base, out + base);
  } else {
    const size_t baseIn  = ((size_t)b * T + (t0 - W)) * RS2 + col;
    const size_t baseOut = ((size_t)b * T + t0) * RS2 + col;
    run_chunk<true>(x + baseIn, y + baseIn, out + baseOut);
  }
}

extern "C" void kernel_launch(void* const* d_in, const int* in_sizes, int n_in,
                              void* d_out, int out_size, void* d_ws, size_t ws_size,
                              hipStream_t stream) {
  const fx2* x = (const fx2*)d_in[0];
  const fx2* y = (const fx2*)d_in[1];
  fx2* out = (fx2*)d_out;
  const int B = in_sizes[0] / (T * C);       // 16
  const int nblocks = B * NCHUNK * 2;        // 512
  I24DualEMA_kernel<<<dim3(nblocks), dim3(64), 0, stream>>>(x, y, out);
}

// Round 6
// 66.175 us; speedup vs baseline: 1.2739x; 1.0704x over previous
//
#include <hip/hip_runtime.h>

// Dual quantized EMA scan, chunked with redundant warmup.
// State in scaled domain Y = y*2^23: 24-bit quantize = one v_rndne.
// R6: demand-reduction. Model from R1-R5: dur = demand_bytes / 6.4 TB/s once
// >=32 KB/CU of loads in flight (R3/R5 operating point; R4 proved more
// in-flight adds nothing). S 512->1024, W=96 => amp 1.094, demand 427 MB.
// To keep 512 waves (2/CU) at NCHUNK=8: split each C=256 row across 4 blocks
// (1 float/lane), U=32 rows/group so in-flight during compute stays 16 KB/wave.
// Warmup (3 groups, odd) peeled explicitly; main loop processes (b,a) pairs
// with all-static buffer indexing.

constexpr int T = 8192;
constexpr int C = 256;
constexpr int S = 1024;         // chunk length (output rows per block)
constexpr int W = 96;           // warmup length (alpha^96*|state| ~ 5e-4)
constexpr int U = 32;           // rows per load/compute group
constexpr int NCHUNK = T / S;   // 8
constexpr int CSPLIT = 4;       // row split: 64 floats per wave
constexpr int WG = W / U;       // 3 warmup groups
constexpr int NG = WG + S / U;  // 35 total groups

constexpr float ALPHA = 0.95f;

__device__ __forceinline__ void load_group(const float* __restrict__ xq,
                                           const float* __restrict__ yq,
                                           float* xv, float* yv) {
#pragma unroll
  for (int i = 0; i < U; ++i) {
    xv[i] = xq[(size_t)i * C];
    yv[i] = yq[(size_t)i * C];
  }
}

template <bool STORE>
__device__ __forceinline__ void proc_group(float& Y0, float& Y1,
                                           const float* xv, const float* yv,
                                           float* __restrict__ oq) {
  const float K   = (1.0f - ALPHA) * 8388608.0f;  // (1-a) * 2^23
  const float C8  = 1.0f / 256.0f;                // 2^23 -> 2^15 domain
  const float I16 = 1.0f / 32768.0f;
#pragma unroll
  for (int i = 0; i < U; ++i) {
    Y0 = rintf(fmaf(ALPHA, Y0, K * xv[i]));   // 24b EMA (scaled)
    Y1 = rintf(fmaf(ALPHA, Y1, K * yv[i]));
    if (STORE) {
      float o = (rintf(Y0 * C8) + rintf(Y1 * C8)) * I16;
      __builtin_nontemporal_store(o, &oq[(size_t)i * C]);
    }
  }
}

template <bool WARM>
__device__ __forceinline__ void run_chunk(const float* __restrict__ xp,
                                          const float* __restrict__ yp,
                                          float* __restrict__ op) {
  float xa[U], ya[U], xb[U], yb[U];
  float Y0 = 0.0f, Y1 = 0.0f;

  auto xg = [&](int g) { return xp + (size_t)g * U * C; };
  auto yg = [&](int g) { return yp + (size_t)g * U * C; };

  if (WARM) {
    // Peeled warmup: groups 0,1,2 (WG=3). After this, b holds g=3, a holds g=4.
    load_group(xg(0), yg(0), xa, ya);
    load_group(xg(1), yg(1), xb, yb);
    proc_group<false>(Y0, Y1, xa, ya, nullptr);
    load_group(xg(2), yg(2), xa, ya);
    proc_group<false>(Y0, Y1, xb, yb, nullptr);
    load_group(xg(3), yg(3), xb, yb);
    proc_group<false>(Y0, Y1, xa, ya, nullptr);
    load_group(xg(4), yg(4), xa, ya);

#pragma unroll 1
    for (int g = WG; g < NG; g += 2) {     // g = 3,5,...,33 (b holds g, a holds g+1)
      proc_group<true>(Y0, Y1, xb, yb, op + (size_t)(g - WG) * U * C);
      if (g + 2 < NG) load_group(xg(g + 2), yg(g + 2), xb, yb);
      proc_group<true>(Y0, Y1, xa, ya, op + (size_t)(g + 1 - WG) * U * C);
      if (g + 3 < NG) load_group(xg(g + 3), yg(g + 3), xa, ya);
    }
  } else {
    // chunk 0: 32 groups, even pairs.
    load_group(xg(0), yg(0), xa, ya);
#pragma unroll 1
    for (int g = 0; g < NG - WG; g += 2) {
      load_group(xg(g + 1), yg(g + 1), xb, yb);
      proc_group<true>(Y0, Y1, xa, ya, op + (size_t)g * U * C);
      if (g + 2 < NG - WG) load_group(xg(g + 2), yg(g + 2), xa, ya);
      proc_group<true>(Y0, Y1, xb, yb, op + (size_t)(g + 1) * U * C);
    }
  }
}

__global__ __launch_bounds__(64) void I24DualEMA_kernel(const float* __restrict__ x,
                                                        const float* __restrict__ y,
                                                        float* __restrict__ out) {
  const int lane  = threadIdx.x;             // 0..63 -> float column within quarter
  const int bid   = blockIdx.x;
  const int cq    = bid & (CSPLIT - 1);
  const int chunk = (bid >> 2) & (NCHUNK - 1);
  const int b     = bid >> 5;
  const int col   = (cq << 6) | lane;
  const long t0   = (long)chunk * S;

  if (chunk == 0) {
    const size_t base = (size_t)b * T * C + col;
    run_chunk<false>(x + base, y + base, out + base);
  } else {
    const size_t baseIn  = ((size_t)b * T + (t0 - W)) * C + col;
    const size_t baseOut = ((size_t)b * T + t0) * C + col;
    run_chunk<true>(x + baseIn, y + baseIn, out + baseOut);
  }
}

extern "C" void kernel_launch(void* const* d_in, const int* in_sizes, int n_in,
                              void* d_out, int out_size, void* d_ws, size_t ws_size,
                              hipStream_t stream) {
  const float* x = (const float*)d_in[0];
  const float* y = (const float*)d_in[1];
  float* out = (float*)d_out;
  const int B = in_sizes[0] / (T * C);          // 16
  const int nblocks = B * NCHUNK * CSPLIT;      // 512
  I24DualEMA_kernel<<<dim3(nblocks), dim3(64), 0, stream>>>(x, y, out);
}